// Round 3
// baseline (3318.600 us; speedup 1.0000x reference)
//
#include <hip/hip_runtime.h>

#define CDIM 64

// Copy inputs into residual slots of d_out and current-emb storage.
__global__ void init_kernel(const float* __restrict__ user_emb,
                            const float* __restrict__ ent_emb,
                            float* __restrict__ outUserRes,   // d_out[0 : nuC]
                            float* __restrict__ outNodeRes,   // d_out[nnC : 2nnC]
                            float* __restrict__ entCur,       // d_out[nuC : nnC]
                            float* __restrict__ nodeCurU,     // ws
                            long nuC, long neC) {
    long i = (long)blockIdx.x * blockDim.x + threadIdx.x;
    if (i < nuC) {
        float v = user_emb[i];
        outUserRes[i] = v; outNodeRes[i] = v; nodeCurU[i] = v;
    }
    if (i < neC) {
        float v = ent_emb[i];
        entCur[i] = v; outNodeRes[nuC + i] = v;
    }
}

__global__ void count_kernel(const int* __restrict__ idx, float* __restrict__ cnt, int n) {
    int e = blockIdx.x * blockDim.x + threadIdx.x;
    if (e < n) atomicAdd(&cnt[idx[e]], 1.0f);
}

__global__ void recip_kernel(float* __restrict__ cnt, int n) {
    int i = blockIdx.x * blockDim.x + threadIdx.x;
    if (i < n) cnt[i] = 1.0f / fmaxf(cnt[i], 1.0f);
}

// One wave (64 lanes) per edge; lane = channel.
__global__ void ent_scatter(const float* __restrict__ entCur,
                            const float* __restrict__ weight,
                            const int* __restrict__ head,
                            const int* __restrict__ tail,
                            const int* __restrict__ etype,
                            float* __restrict__ agg, int E) {
    int e = blockIdx.x * 4 + (threadIdx.x >> 6);
    int c = threadIdx.x & 63;
    if (e >= E) return;
    int h = head[e], t = tail[e], r = etype[e] - 1;
    float v = entCur[(long)t * CDIM + c] * weight[r * CDIM + c];
    atomicAdd(&agg[(long)h * CDIM + c], v);
}

__global__ void node_scatter(const float* __restrict__ nodeCurU,
                             const float* __restrict__ entCur,
                             const float* __restrict__ extraW,
                             const int* __restrict__ eh,
                             const int* __restrict__ et,
                             const int* __restrict__ xtype,
                             float* __restrict__ agg, int E2, int NU) {
    int e = blockIdx.x * 4 + (threadIdx.x >> 6);
    int c = threadIdx.x & 63;
    if (e >= E2) return;
    int h = eh[e], t = et[e], r = xtype[e];
    const float* src = (t < NU) ? (nodeCurU + (long)t * CDIM)
                                : (entCur + (long)(t - NU) * CDIM);
    float v = src[c] * extraW[r * CDIM + c];
    atomicAdd(&agg[(long)h * CDIM + c], v);
}

__global__ void mean_mul(float* __restrict__ agg, const float* __restrict__ rcnt, long nElem) {
    long i = (long)blockIdx.x * blockDim.x + threadIdx.x;
    if (i < nElem) agg[i] *= rcnt[i >> 6];
}

__global__ void user_scatter(const float* __restrict__ entMean,
                             const float* __restrict__ imVal,
                             const int* __restrict__ imRow,
                             const int* __restrict__ imCol,
                             float* __restrict__ aggUser, int NNZ) {
    int e = blockIdx.x * 4 + (threadIdx.x >> 6);
    int c = threadIdx.x & 63;
    if (e >= NNZ) return;
    int r = imRow[e], col = imCol[e];
    float v = entMean[(long)col * CDIM + c] * imVal[e];
    atomicAdd(&aggUser[(long)r * CDIM + c], v);
}

__device__ __forceinline__ float row_norm_val(float v) {
    float s = v * v;
    #pragma unroll
    for (int o = 32; o > 0; o >>= 1) s += __shfl_xor(s, o, 64);
    return sqrtf(s);
}

// Normalize entity rows -> entCur (d_out slot, final hop leaves the answer).
__global__ void norm_ent(const float* __restrict__ agg,
                         float* __restrict__ entCur,
                         int NE) {
    int row = blockIdx.x * 4 + (threadIdx.x >> 6);
    int c = threadIdx.x & 63;
    if (row >= NE) return;
    long idx = (long)row * CDIM + c;
    float v = agg[idx];
    entCur[idx] = v / fmaxf(row_norm_val(v), 1e-12f);
}

// Normalize node rows -> accumulate residual in d_out; first NU rows -> nodeCurU.
__global__ void norm_node(const float* __restrict__ agg,
                          float* __restrict__ nodeCurU,
                          float* __restrict__ resOut,
                          int NN, int NU) {
    int row = blockIdx.x * 4 + (threadIdx.x >> 6);
    int c = threadIdx.x & 63;
    if (row >= NN) return;
    long idx = (long)row * CDIM + c;
    float v = agg[idx];
    float out = v / fmaxf(row_norm_val(v), 1e-12f);
    resOut[idx] += out;
    if (row < NU) nodeCurU[idx] = out;
}

// Normalize user rows -> accumulate residual in d_out.
__global__ void norm_user(const float* __restrict__ agg,
                          float* __restrict__ resOut,
                          int NU) {
    int row = blockIdx.x * 4 + (threadIdx.x >> 6);
    int c = threadIdx.x & 63;
    if (row >= NU) return;
    long idx = (long)row * CDIM + c;
    float v = agg[idx];
    resOut[idx] += v / fmaxf(row_norm_val(v), 1e-12f);
}

// Debug: report ws_size (in MB) through the output if scratch is too small.
__global__ void fill_debug(float* __restrict__ out, long n, float val) {
    long i = (long)blockIdx.x * blockDim.x + threadIdx.x;
    if (i < n) out[i] = val;
}

extern "C" void kernel_launch(void* const* d_in, const int* in_sizes, int n_in,
                              void* d_out, int out_size, void* d_ws, size_t ws_size,
                              hipStream_t stream) {
    const float* user_emb = (const float*)d_in[0];
    const float* ent_emb  = (const float*)d_in[1];
    const float* weight   = (const float*)d_in[2];
    const float* extraW   = (const float*)d_in[3];
    const float* imVal    = (const float*)d_in[4];
    const int*   eidx     = (const int*)d_in[5];
    const int*   etype    = (const int*)d_in[6];
    const int*   xidx     = (const int*)d_in[7];
    const int*   xtype    = (const int*)d_in[8];
    const int*   imRow    = (const int*)d_in[9];
    const int*   imCol    = (const int*)d_in[10];

    const int NU  = in_sizes[0] / CDIM;
    const int NE  = in_sizes[1] / CDIM;
    const int NN  = NU + NE;
    const int E   = in_sizes[5] / 2;
    const int E2  = in_sizes[7] / 2;
    const int NNZ = in_sizes[4];
    const long nuC = (long)NU * CDIM, neC = (long)NE * CDIM, nnC = (long)NN * CDIM;

    float* out = (float*)d_out;

    // ---- workspace layout (all fp32) ----
    size_t required = (size_t)(neC + nnC + nuC) * 4   // aggEnt, aggNode, aggUser (contiguous)
                    + (size_t)nuC * 4                 // nodeCurU
                    + (size_t)(NE + NN) * 4;          // rcntEnt, rcntNode (contiguous)
    if (ws_size < required) {
        long total = 2 * nnC;
        fill_debug<<<(total + 255) / 256, 256, 0, stream>>>(out, total, (float)(ws_size >> 20));
        return;
    }

    char* w = (char*)d_ws;
    float* aggEnt   = (float*)w;  w += neC * 4;
    float* aggNode  = (float*)w;  w += nnC * 4;
    float* aggUser  = (float*)w;  w += nuC * 4;
    float* nodeCurU = (float*)w;  w += nuC * 4;
    float* rcntEnt  = (float*)w;  w += (size_t)NE * 4;
    float* rcntNode = (float*)w;  w += (size_t)NN * 4;

    const int* head = eidx;  const int* tail = eidx + E;
    const int* eh   = xidx;  const int* et   = xidx + E2;

    float* outUserRes = out;            // [0 : nuC]       user_res accumulation
    float* entCur     = out + nuC;      // [nuC : nnC]     current entity emb; final hop = output
    float* outNodeRes = out + nnC;      // [nnC : 2nnC]    node_res accumulation

    // hop-invariant reciprocal counts
    hipMemsetAsync(rcntEnt, 0, (size_t)(NE + NN) * 4, stream);
    long initN = (nuC > neC ? nuC : neC);
    init_kernel<<<(initN + 255) / 256, 256, 0, stream>>>(
        user_emb, ent_emb, outUserRes, outNodeRes, entCur, nodeCurU, nuC, neC);
    count_kernel<<<(E  + 255) / 256, 256, 0, stream>>>(head, rcntEnt, E);
    count_kernel<<<(E2 + 255) / 256, 256, 0, stream>>>(eh,   rcntNode, E2);
    recip_kernel<<<(NE + 255) / 256, 256, 0, stream>>>(rcntEnt, NE);
    recip_kernel<<<(NN + 255) / 256, 256, 0, stream>>>(rcntNode, NN);

    for (int hop = 0; hop < 3; ++hop) {
        // zero all three agg buffers (contiguous)
        hipMemsetAsync(aggEnt, 0, (size_t)(neC + nnC + nuC) * 4, stream);

        ent_scatter<<<(E + 3) / 4, 256, 0, stream>>>(
            entCur, weight, head, tail, etype, aggEnt, E);
        node_scatter<<<(E2 + 3) / 4, 256, 0, stream>>>(
            nodeCurU, entCur, extraW, eh, et, xtype, aggNode, E2, NU);

        mean_mul<<<(neC + 255) / 256, 256, 0, stream>>>(aggEnt, rcntEnt, neC);
        mean_mul<<<(nnC + 255) / 256, 256, 0, stream>>>(aggNode, rcntNode, nnC);

        // user segment_sum uses the PRE-normalization entity mean
        user_scatter<<<(NNZ + 3) / 4, 256, 0, stream>>>(
            aggEnt, imVal, imRow, imCol, aggUser, NNZ);

        norm_ent<<<(NE + 3) / 4, 256, 0, stream>>>(aggEnt, entCur, NE);
        norm_node<<<(NN + 3) / 4, 256, 0, stream>>>(aggNode, nodeCurU, outNodeRes, NN, NU);
        norm_user<<<(NU + 3) / 4, 256, 0, stream>>>(aggUser, outUserRes, NU);
    }
}

// Round 4
// 1974.775 us; speedup vs baseline: 1.6805x; 1.6805x over previous
//
#include <hip/hip_runtime.h>

#define CDIM 64
#define SCAN_B 256

// ---------------- init: residual slots of d_out ----------------
__global__ void init_kernel(const float* __restrict__ user_emb,
                            const float* __restrict__ ent_emb,
                            float* __restrict__ outUserRes,   // d_out[0 : nuC]
                            float* __restrict__ outNodeRes,   // d_out[nnC : 2nnC]
                            long nuC, long neC) {
    long i = (long)blockIdx.x * blockDim.x + threadIdx.x;
    if (i < nuC) { float v = user_emb[i]; outUserRes[i] = v; outNodeRes[i] = v; }
    if (i < neC) { outNodeRes[nuC + i] = ent_emb[i]; }
}

// ---------------- CSR build ----------------
__global__ void count_kernel(const int* __restrict__ idx, int* __restrict__ cnt, int n) {
    int e = blockIdx.x * blockDim.x + threadIdx.x;
    if (e < n) atomicAdd(&cnt[idx[e]], 1);
}

// block-level exclusive scan (Hillis-Steele in LDS), emits block totals
__global__ void scan1(const int* __restrict__ in, int* __restrict__ out,
                      int* __restrict__ bsum, int n) {
    __shared__ int tmp[SCAN_B];
    int x = threadIdx.x;
    int i = blockIdx.x * SCAN_B + x;
    int v = (i < n) ? in[i] : 0;
    tmp[x] = v; __syncthreads();
    for (int off = 1; off < SCAN_B; off <<= 1) {
        int t = (x >= off) ? tmp[x - off] : 0;
        __syncthreads();
        tmp[x] += t;
        __syncthreads();
    }
    if (i < n) out[i] = tmp[x] - v;             // exclusive
    if (x == SCAN_B - 1) bsum[blockIdx.x] = tmp[x];
}

// single-block exclusive scan of block totals (nb <= 1024)
__global__ void scan2(int* __restrict__ bsum, int nb) {
    __shared__ int tmp[1024];
    int x = threadIdx.x;
    int v = (x < nb) ? bsum[x] : 0;
    tmp[x] = v; __syncthreads();
    for (int off = 1; off < 1024; off <<= 1) {
        int t = (x >= off) ? tmp[x - off] : 0;
        __syncthreads();
        tmp[x] += t;
        __syncthreads();
    }
    if (x < nb) bsum[x] = tmp[x] - v;           // exclusive
}

__global__ void scan3(int* __restrict__ out, const int* __restrict__ bsum, int n) {
    int i = blockIdx.x * SCAN_B + threadIdx.x;
    if (i < n) out[i] += bsum[blockIdx.x];
}

// fill CSR with packed (type<<27 | src); cursor = offsets array (becomes "end" array)
__global__ void fill_pair(const int* __restrict__ dst, const int* __restrict__ src,
                          const int* __restrict__ typ, int typeBias,
                          int* __restrict__ cursor, int* __restrict__ pairs, int n) {
    int e = blockIdx.x * blockDim.x + threadIdx.x;
    if (e >= n) return;
    int slot = atomicAdd(&cursor[dst[e]], 1);
    pairs[slot] = ((typ[e] + typeBias) << 27) | src[e];
}

__global__ void fill_user(const int* __restrict__ row, const int* __restrict__ col,
                          const float* __restrict__ val,
                          int* __restrict__ cursor,
                          int* __restrict__ ucol, float* __restrict__ uval, int n) {
    int e = blockIdx.x * blockDim.x + threadIdx.x;
    if (e >= n) return;
    int slot = atomicAdd(&cursor[row[e]], 1);
    ucol[slot] = col[e];
    uval[slot] = val[e];
}

// ---------------- gathers (one wave per dest row, lane = channel) ----------------
__device__ __forceinline__ float wave_l2(float v) {
    float q = v * v;
    #pragma unroll
    for (int o = 32; o > 0; o >>= 1) q += __shfl_xor(q, o, 64);
    return sqrtf(q);
}

__global__ void ent_gather(const float* __restrict__ entCur,
                           const float* __restrict__ weight,
                           const int* __restrict__ endArr,
                           const int* __restrict__ pairs,
                           float* __restrict__ entNew,
                           float* __restrict__ entNorm,
                           int NE) {
    __shared__ float wlds[15 * CDIM];
    for (int i = threadIdx.x; i < 15 * CDIM; i += blockDim.x) wlds[i] = weight[i];
    __syncthreads();
    int row = blockIdx.x * (blockDim.x >> 6) + (threadIdx.x >> 6);
    int c = threadIdx.x & 63;
    if (row >= NE) return;
    int start = row ? endArr[row - 1] : 0;
    int end = endArr[row];
    float s = 0.f;
    for (int j = start; j < end; ++j) {
        int p = pairs[j];                       // wave-uniform broadcast load
        int src = p & 0x07FFFFFF;
        int r = ((unsigned)p) >> 27;
        s += entCur[(long)src * CDIM + c] * wlds[r * CDIM + c];
    }
    float mean = s / fmaxf((float)(end - start), 1.0f);
    float n = fmaxf(wave_l2(mean), 1e-12f);
    entNew[(long)row * CDIM + c] = mean / n;
    if (c == 0) entNorm[row] = n;               // for exact pre-norm mean reconstruction
}

__global__ void node_gather(const float* __restrict__ nodeUold,
                            const float* __restrict__ entCur,
                            const float* __restrict__ extraW,
                            const int* __restrict__ endArr,
                            const int* __restrict__ pairs,
                            float* __restrict__ nodeUnew,
                            float* __restrict__ resOut,
                            int NN, int NU) {
    __shared__ float wlds[16 * CDIM];
    for (int i = threadIdx.x; i < 16 * CDIM; i += blockDim.x) wlds[i] = extraW[i];
    __syncthreads();
    int row = blockIdx.x * (blockDim.x >> 6) + (threadIdx.x >> 6);
    int c = threadIdx.x & 63;
    if (row >= NN) return;
    int start = row ? endArr[row - 1] : 0;
    int end = endArr[row];
    float s = 0.f;
    for (int j = start; j < end; ++j) {
        int p = pairs[j];
        int src = p & 0x07FFFFFF;
        int r = ((unsigned)p) >> 27;
        const float* base = (src < NU) ? (nodeUold + (long)src * CDIM)
                                       : (entCur + (long)(src - NU) * CDIM);
        s += base[c] * wlds[r * CDIM + c];
    }
    float mean = s / fmaxf((float)(end - start), 1.0f);
    float n = fmaxf(wave_l2(mean), 1e-12f);
    float out = mean / n;
    long idx = (long)row * CDIM + c;
    resOut[idx] += out;
    if (row < NU) nodeUnew[idx] = out;
}

__global__ void user_gather(const float* __restrict__ entNew,
                            const float* __restrict__ entNorm,
                            const int* __restrict__ endArr,
                            const int* __restrict__ ucol,
                            const float* __restrict__ uval,
                            float* __restrict__ userRes,
                            int NU) {
    int row = blockIdx.x * (blockDim.x >> 6) + (threadIdx.x >> 6);
    int c = threadIdx.x & 63;
    if (row >= NU) return;
    int start = row ? endArr[row - 1] : 0;
    int end = endArr[row];
    float s = 0.f;
    for (int j = start; j < end; ++j) {
        int col = ucol[j];
        float f = entNorm[col] * uval[j];       // reconstruct pre-norm mean scale
        s += entNew[(long)col * CDIM + c] * f;
    }
    // segment_sum (NOT mean), then l2norm, accumulate residual
    float n = fmaxf(wave_l2(s), 1e-12f);
    userRes[(long)row * CDIM + c] += s / n;
}

__global__ void fill_debug(float* __restrict__ out, long n, float val) {
    long i = (long)blockIdx.x * blockDim.x + threadIdx.x;
    if (i < n) out[i] = val;
}

extern "C" void kernel_launch(void* const* d_in, const int* in_sizes, int n_in,
                              void* d_out, int out_size, void* d_ws, size_t ws_size,
                              hipStream_t stream) {
    const float* user_emb = (const float*)d_in[0];
    const float* ent_emb  = (const float*)d_in[1];
    const float* weight   = (const float*)d_in[2];
    const float* extraW   = (const float*)d_in[3];
    const float* imVal    = (const float*)d_in[4];
    const int*   eidx     = (const int*)d_in[5];
    const int*   etype    = (const int*)d_in[6];
    const int*   xidx     = (const int*)d_in[7];
    const int*   xtype    = (const int*)d_in[8];
    const int*   imRow    = (const int*)d_in[9];
    const int*   imCol    = (const int*)d_in[10];

    const int NU  = in_sizes[0] / CDIM;
    const int NE  = in_sizes[1] / CDIM;
    const int NN  = NU + NE;
    const int E   = in_sizes[5] / 2;
    const int E2  = in_sizes[7] / 2;
    const int NNZ = in_sizes[4];
    const long nuC = (long)NU * CDIM, neC = (long)NE * CDIM, nnC = (long)NN * CDIM;

    float* out = (float*)d_out;
    float* outUserRes = out;            // [0 : nuC]
    float* entOut     = out + nuC;      // [nuC : nnC]  ping-pong slot; ends holding final ent
    float* outNodeRes = out + nnC;      // [nnC : 2nnC]

    // ---- workspace layout ----
    size_t required = (size_t)neC * 4                       // entA
                    + (size_t)nuC * 4 * 2                   // nodeU_A, nodeU_B
                    + (size_t)NE * 4                        // entNorm
                    + (size_t)(NE + NN + NU) * 4 * 2        // counts + offsets
                    + (size_t)(E + E2) * 4                  // packed pairs
                    + (size_t)NNZ * 8                       // ucol + uval
                    + 1024 * 4;                             // scan partials
    if (ws_size < required) {
        long total = 2 * nnC;
        fill_debug<<<(total + 255) / 256, 256, 0, stream>>>(out, total, (float)(ws_size >> 20));
        return;
    }

    char* w = (char*)d_ws;
    float* entA     = (float*)w; w += (size_t)neC * 4;
    float* nodeU_A  = (float*)w; w += (size_t)nuC * 4;
    float* nodeU_B  = (float*)w; w += (size_t)nuC * 4;
    float* entNorm  = (float*)w; w += (size_t)NE * 4;
    int* cntEnt   = (int*)w; w += (size_t)NE * 4;   // counts contiguous -> one memset
    int* cntNode  = (int*)w; w += (size_t)NN * 4;
    int* cntUser  = (int*)w; w += (size_t)NU * 4;
    int* arrEnt   = (int*)w; w += (size_t)NE * 4;
    int* arrNode  = (int*)w; w += (size_t)NN * 4;
    int* arrUser  = (int*)w; w += (size_t)NU * 4;
    int* pairsEnt  = (int*)w; w += (size_t)E * 4;
    int* pairsNode = (int*)w; w += (size_t)E2 * 4;
    int* ucol = (int*)w; w += (size_t)NNZ * 4;
    float* uval = (float*)w; w += (size_t)NNZ * 4;
    int* part = (int*)w; w += 1024 * 4;

    const int* head = eidx;  const int* tail = eidx + E;
    const int* eh   = xidx;  const int* et   = xidx + E2;

    // ---- one-time (per launch) CSR build ----
    hipMemsetAsync(cntEnt, 0, (size_t)(NE + NN + NU) * 4, stream);
    long initN = (nuC > neC ? nuC : neC);
    init_kernel<<<(initN + 255) / 256, 256, 0, stream>>>(
        user_emb, ent_emb, outUserRes, outNodeRes, nuC, neC);

    count_kernel<<<(E   + 255) / 256, 256, 0, stream>>>(head,  cntEnt,  E);
    count_kernel<<<(E2  + 255) / 256, 256, 0, stream>>>(eh,    cntNode, E2);
    count_kernel<<<(NNZ + 255) / 256, 256, 0, stream>>>(imRow, cntUser, NNZ);

    // scans: counts -> exclusive offsets
    {
        int nb;
        nb = (NE + SCAN_B - 1) / SCAN_B;
        scan1<<<nb, SCAN_B, 0, stream>>>(cntEnt, arrEnt, part, NE);
        scan2<<<1, 1024, 0, stream>>>(part, nb);
        scan3<<<nb, SCAN_B, 0, stream>>>(arrEnt, part, NE);
        nb = (NN + SCAN_B - 1) / SCAN_B;
        scan1<<<nb, SCAN_B, 0, stream>>>(cntNode, arrNode, part, NN);
        scan2<<<1, 1024, 0, stream>>>(part, nb);
        scan3<<<nb, SCAN_B, 0, stream>>>(arrNode, part, NN);
        nb = (NU + SCAN_B - 1) / SCAN_B;
        scan1<<<nb, SCAN_B, 0, stream>>>(cntUser, arrUser, part, NU);
        scan2<<<1, 1024, 0, stream>>>(part, nb);
        scan3<<<nb, SCAN_B, 0, stream>>>(arrUser, part, NU);
    }

    // fills (cursor arrays become inclusive-end arrays)
    fill_pair<<<(E + 255) / 256, 256, 0, stream>>>(head, tail, etype, -1, arrEnt, pairsEnt, E);
    fill_pair<<<(E2 + 255) / 256, 256, 0, stream>>>(eh, et, xtype, 0, arrNode, pairsNode, E2);
    fill_user<<<(NNZ + 255) / 256, 256, 0, stream>>>(imRow, imCol, imVal, arrUser, ucol, uval, NNZ);

    // ---- 3 hops of gathers ----
    // ent ping-pong: in -> entOut -> entA -> entOut (final lands in d_out)
    // nodeU ping-pong: user_emb(in) -> A -> B -> A
    const float* entCurP  = ent_emb;   float* entNewP  = entOut;
    const float* nodeOldP = user_emb;  float* nodeNewP = nodeU_A;

    for (int hop = 0; hop < 3; ++hop) {
        ent_gather<<<(NE + 3) / 4, 256, 0, stream>>>(
            entCurP, weight, arrEnt, pairsEnt, entNewP, entNorm, NE);
        node_gather<<<(NN + 3) / 4, 256, 0, stream>>>(
            nodeOldP, entCurP, extraW, arrNode, pairsNode, nodeNewP, outNodeRes, NN, NU);
        user_gather<<<(NU + 3) / 4, 256, 0, stream>>>(
            entNewP, entNorm, arrUser, ucol, uval, outUserRes, NU);

        if (hop == 0) {
            entCurP = entOut;  entNewP = entA;
            nodeOldP = nodeU_A; nodeNewP = nodeU_B;
        } else if (hop == 1) {
            entCurP = entA;    entNewP = entOut;
            nodeOldP = nodeU_B; nodeNewP = nodeU_A;
        }
    }
}

// Round 5
// 1258.385 us; speedup vs baseline: 2.6372x; 1.5693x over previous
//
#include <hip/hip_runtime.h>

#define CDIM 64
#define SCAN_B 256

// ---------------- init: residual slots of d_out ----------------
__global__ void init_kernel(const float4* __restrict__ user_emb,
                            const float4* __restrict__ ent_emb,
                            float4* __restrict__ outUserRes,   // d_out[0 : nuC]
                            float4* __restrict__ outNodeRes,   // d_out[nnC : 2nnC]
                            long nuC4, long neC4) {
    long i = (long)blockIdx.x * blockDim.x + threadIdx.x;
    if (i < nuC4) { float4 v = user_emb[i]; outUserRes[i] = v; outNodeRes[i] = v; }
    if (i < neC4) { outNodeRes[nuC4 + i] = ent_emb[i]; }
}

// ---------------- CSR build ----------------
__global__ void count_kernel(const int* __restrict__ idx, int* __restrict__ cnt, int n) {
    int e = blockIdx.x * blockDim.x + threadIdx.x;
    if (e < n) atomicAdd(&cnt[idx[e]], 1);
}

__global__ void scan1(const int* __restrict__ in, int* __restrict__ out,
                      int* __restrict__ bsum, int n) {
    __shared__ int tmp[SCAN_B];
    int x = threadIdx.x;
    int i = blockIdx.x * SCAN_B + x;
    int v = (i < n) ? in[i] : 0;
    tmp[x] = v; __syncthreads();
    for (int off = 1; off < SCAN_B; off <<= 1) {
        int t = (x >= off) ? tmp[x - off] : 0;
        __syncthreads();
        tmp[x] += t;
        __syncthreads();
    }
    if (i < n) out[i] = tmp[x] - v;             // exclusive
    if (x == SCAN_B - 1) bsum[blockIdx.x] = tmp[x];
}

__global__ void scan2(int* __restrict__ bsum, int nb) {
    __shared__ int tmp[1024];
    int x = threadIdx.x;
    int v = (x < nb) ? bsum[x] : 0;
    tmp[x] = v; __syncthreads();
    for (int off = 1; off < 1024; off <<= 1) {
        int t = (x >= off) ? tmp[x - off] : 0;
        __syncthreads();
        tmp[x] += t;
        __syncthreads();
    }
    if (x < nb) bsum[x] = tmp[x] - v;           // exclusive
}

__global__ void scan3(int* __restrict__ out, const int* __restrict__ bsum, int n) {
    int i = blockIdx.x * SCAN_B + threadIdx.x;
    if (i < n) out[i] += bsum[blockIdx.x];
}

__global__ void fill_pair(const int* __restrict__ dst, const int* __restrict__ src,
                          const int* __restrict__ typ, int typeBias,
                          int* __restrict__ cursor, int* __restrict__ pairs, int n) {
    int e = blockIdx.x * blockDim.x + threadIdx.x;
    if (e >= n) return;
    int slot = atomicAdd(&cursor[dst[e]], 1);
    pairs[slot] = ((typ[e] + typeBias) << 27) | src[e];
}

__global__ void fill_user(const int* __restrict__ row, const int* __restrict__ col,
                          const float* __restrict__ val,
                          int* __restrict__ cursor,
                          int* __restrict__ ucol, float* __restrict__ uval, int n) {
    int e = blockIdx.x * blockDim.x + threadIdx.x;
    if (e >= n) return;
    int slot = atomicAdd(&cursor[row[e]], 1);
    ucol[slot] = col[e];
    uval[slot] = val[e];
}

// ---------------- gathers ----------------
// Layout: one wave per destination row. lane = 16*q + l.
//   q (0..3)  = edge slot: 4 edges processed per iteration
//   l (0..15) = float4 channel group (covers channels 4l..4l+3)

__global__ void ent_gather(const float* __restrict__ entCur,
                           const float4* __restrict__ weight,
                           const int* __restrict__ endArr,
                           const int* __restrict__ pairs,
                           float* __restrict__ entNew,
                           float* __restrict__ entNorm,
                           int NE) {
    __shared__ float4 wlds[15 * 16];
    for (int i = threadIdx.x; i < 15 * 16; i += blockDim.x) wlds[i] = weight[i];
    __syncthreads();
    int row = blockIdx.x * (blockDim.x >> 6) + (threadIdx.x >> 6);
    int lane = threadIdx.x & 63;
    int q = lane >> 4, l = lane & 15;
    if (row >= NE) return;
    int start = row ? endArr[row - 1] : 0;
    int end = endArr[row];
    float4 acc = make_float4(0.f, 0.f, 0.f, 0.f);
    for (int j = start + q; j < end; j += 4) {
        int p = pairs[j];
        int src = p & 0x07FFFFFF;
        int r = ((unsigned)p) >> 27;
        float4 v = ((const float4*)(entCur + (long)src * CDIM))[l];
        float4 w = wlds[r * 16 + l];
        acc.x += v.x * w.x; acc.y += v.y * w.y;
        acc.z += v.z * w.z; acc.w += v.w * w.w;
    }
    #pragma unroll
    for (int off = 16; off < 64; off <<= 1) {
        acc.x += __shfl_xor(acc.x, off, 64);
        acc.y += __shfl_xor(acc.y, off, 64);
        acc.z += __shfl_xor(acc.z, off, 64);
        acc.w += __shfl_xor(acc.w, off, 64);
    }
    float inv = 1.0f / fmaxf((float)(end - start), 1.0f);
    float4 mean = make_float4(acc.x * inv, acc.y * inv, acc.z * inv, acc.w * inv);
    float q2 = mean.x * mean.x + mean.y * mean.y + mean.z * mean.z + mean.w * mean.w;
    #pragma unroll
    for (int off = 1; off < 16; off <<= 1) q2 += __shfl_xor(q2, off, 64);
    float n = fmaxf(sqrtf(q2), 1e-12f);
    float rn = 1.0f / n;
    if (q == 0) {
        ((float4*)(entNew + (long)row * CDIM))[l] =
            make_float4(mean.x * rn, mean.y * rn, mean.z * rn, mean.w * rn);
        if (l == 0) entNorm[row] = n;
    }
}

__global__ void node_gather(const float* __restrict__ nodeUold,
                            const float* __restrict__ entCur,
                            const float4* __restrict__ extraW,
                            const int* __restrict__ endArr,
                            const int* __restrict__ pairs,
                            float* __restrict__ nodeUnew,
                            float* __restrict__ resOut,
                            int NN, int NU) {
    __shared__ float4 wlds[16 * 16];
    for (int i = threadIdx.x; i < 16 * 16; i += blockDim.x) wlds[i] = extraW[i];
    __syncthreads();
    int row = blockIdx.x * (blockDim.x >> 6) + (threadIdx.x >> 6);
    int lane = threadIdx.x & 63;
    int q = lane >> 4, l = lane & 15;
    if (row >= NN) return;
    int start = row ? endArr[row - 1] : 0;
    int end = endArr[row];
    float4 acc = make_float4(0.f, 0.f, 0.f, 0.f);
    for (int j = start + q; j < end; j += 4) {
        int p = pairs[j];
        int src = p & 0x07FFFFFF;
        int r = ((unsigned)p) >> 27;
        const float* base = (src < NU) ? (nodeUold + (long)src * CDIM)
                                       : (entCur + (long)(src - NU) * CDIM);
        float4 v = ((const float4*)base)[l];
        float4 w = wlds[r * 16 + l];
        acc.x += v.x * w.x; acc.y += v.y * w.y;
        acc.z += v.z * w.z; acc.w += v.w * w.w;
    }
    #pragma unroll
    for (int off = 16; off < 64; off <<= 1) {
        acc.x += __shfl_xor(acc.x, off, 64);
        acc.y += __shfl_xor(acc.y, off, 64);
        acc.z += __shfl_xor(acc.z, off, 64);
        acc.w += __shfl_xor(acc.w, off, 64);
    }
    float inv = 1.0f / fmaxf((float)(end - start), 1.0f);
    float4 mean = make_float4(acc.x * inv, acc.y * inv, acc.z * inv, acc.w * inv);
    float q2 = mean.x * mean.x + mean.y * mean.y + mean.z * mean.z + mean.w * mean.w;
    #pragma unroll
    for (int off = 1; off < 16; off <<= 1) q2 += __shfl_xor(q2, off, 64);
    float rn = 1.0f / fmaxf(sqrtf(q2), 1e-12f);
    if (q == 0) {
        float4 o = make_float4(mean.x * rn, mean.y * rn, mean.z * rn, mean.w * rn);
        float4* resRow = (float4*)(resOut + (long)row * CDIM);
        float4 rv = resRow[l];
        resRow[l] = make_float4(rv.x + o.x, rv.y + o.y, rv.z + o.z, rv.w + o.w);
        if (row < NU) ((float4*)(nodeUnew + (long)row * CDIM))[l] = o;
    }
}

__global__ void user_gather(const float* __restrict__ entNew,
                            const float* __restrict__ entNorm,
                            const int* __restrict__ endArr,
                            const int* __restrict__ ucol,
                            const float* __restrict__ uval,
                            float* __restrict__ userRes,
                            int NU) {
    int row = blockIdx.x * (blockDim.x >> 6) + (threadIdx.x >> 6);
    int lane = threadIdx.x & 63;
    int q = lane >> 4, l = lane & 15;
    if (row >= NU) return;
    int start = row ? endArr[row - 1] : 0;
    int end = endArr[row];
    float4 acc = make_float4(0.f, 0.f, 0.f, 0.f);
    for (int j = start + q; j < end; j += 4) {
        int col = ucol[j];
        float f = entNorm[col] * uval[j];       // reconstruct pre-norm mean scale
        float4 v = ((const float4*)(entNew + (long)col * CDIM))[l];
        acc.x += v.x * f; acc.y += v.y * f;
        acc.z += v.z * f; acc.w += v.w * f;
    }
    #pragma unroll
    for (int off = 16; off < 64; off <<= 1) {
        acc.x += __shfl_xor(acc.x, off, 64);
        acc.y += __shfl_xor(acc.y, off, 64);
        acc.z += __shfl_xor(acc.z, off, 64);
        acc.w += __shfl_xor(acc.w, off, 64);
    }
    float q2 = acc.x * acc.x + acc.y * acc.y + acc.z * acc.z + acc.w * acc.w;
    #pragma unroll
    for (int off = 1; off < 16; off <<= 1) q2 += __shfl_xor(q2, off, 64);
    float rn = 1.0f / fmaxf(sqrtf(q2), 1e-12f);
    if (q == 0) {
        float4* resRow = (float4*)(userRes + (long)row * CDIM);
        float4 rv = resRow[l];
        resRow[l] = make_float4(rv.x + acc.x * rn, rv.y + acc.y * rn,
                                rv.z + acc.z * rn, rv.w + acc.w * rn);
    }
}

__global__ void fill_debug(float* __restrict__ out, long n, float val) {
    long i = (long)blockIdx.x * blockDim.x + threadIdx.x;
    if (i < n) out[i] = val;
}

extern "C" void kernel_launch(void* const* d_in, const int* in_sizes, int n_in,
                              void* d_out, int out_size, void* d_ws, size_t ws_size,
                              hipStream_t stream) {
    const float* user_emb = (const float*)d_in[0];
    const float* ent_emb  = (const float*)d_in[1];
    const float* weight   = (const float*)d_in[2];
    const float* extraW   = (const float*)d_in[3];
    const float* imVal    = (const float*)d_in[4];
    const int*   eidx     = (const int*)d_in[5];
    const int*   etype    = (const int*)d_in[6];
    const int*   xidx     = (const int*)d_in[7];
    const int*   xtype    = (const int*)d_in[8];
    const int*   imRow    = (const int*)d_in[9];
    const int*   imCol    = (const int*)d_in[10];

    const int NU  = in_sizes[0] / CDIM;
    const int NE  = in_sizes[1] / CDIM;
    const int NN  = NU + NE;
    const int E   = in_sizes[5] / 2;
    const int E2  = in_sizes[7] / 2;
    const int NNZ = in_sizes[4];
    const long nuC = (long)NU * CDIM, neC = (long)NE * CDIM, nnC = (long)NN * CDIM;

    float* out = (float*)d_out;
    float* outUserRes = out;            // [0 : nuC]
    float* entOut     = out + nuC;      // [nuC : nnC]  ping-pong slot; ends holding final ent
    float* outNodeRes = out + nnC;      // [nnC : 2nnC]

    // ---- workspace layout ----
    size_t required = (size_t)neC * 4                       // entA
                    + (size_t)nuC * 4 * 2                   // nodeU_A, nodeU_B
                    + (size_t)NE * 4                        // entNorm
                    + (size_t)(NE + NN + NU) * 4 * 2        // counts + offsets
                    + (size_t)(E + E2) * 4                  // packed pairs
                    + (size_t)NNZ * 8                       // ucol + uval
                    + 1024 * 4;                             // scan partials
    if (ws_size < required) {
        long total = 2 * nnC;
        fill_debug<<<(total + 255) / 256, 256, 0, stream>>>(out, total, (float)(ws_size >> 20));
        return;
    }

    char* w = (char*)d_ws;
    float* entA     = (float*)w; w += (size_t)neC * 4;
    float* nodeU_A  = (float*)w; w += (size_t)nuC * 4;
    float* nodeU_B  = (float*)w; w += (size_t)nuC * 4;
    float* entNorm  = (float*)w; w += (size_t)NE * 4;
    int* cntEnt   = (int*)w; w += (size_t)NE * 4;   // counts contiguous -> one memset
    int* cntNode  = (int*)w; w += (size_t)NN * 4;
    int* cntUser  = (int*)w; w += (size_t)NU * 4;
    int* arrEnt   = (int*)w; w += (size_t)NE * 4;
    int* arrNode  = (int*)w; w += (size_t)NN * 4;
    int* arrUser  = (int*)w; w += (size_t)NU * 4;
    int* pairsEnt  = (int*)w; w += (size_t)E * 4;
    int* pairsNode = (int*)w; w += (size_t)E2 * 4;
    int* ucol = (int*)w; w += (size_t)NNZ * 4;
    float* uval = (float*)w; w += (size_t)NNZ * 4;
    int* part = (int*)w; w += 1024 * 4;

    const int* head = eidx;  const int* tail = eidx + E;
    const int* eh   = xidx;  const int* et   = xidx + E2;

    // ---- one-time (per launch) CSR build ----
    hipMemsetAsync(cntEnt, 0, (size_t)(NE + NN + NU) * 4, stream);
    long initN4 = (nuC > neC ? nuC : neC) / 4;
    init_kernel<<<(initN4 + 255) / 256, 256, 0, stream>>>(
        (const float4*)user_emb, (const float4*)ent_emb,
        (float4*)outUserRes, (float4*)outNodeRes, nuC / 4, neC / 4);

    count_kernel<<<(E   + 255) / 256, 256, 0, stream>>>(head,  cntEnt,  E);
    count_kernel<<<(E2  + 255) / 256, 256, 0, stream>>>(eh,    cntNode, E2);
    count_kernel<<<(NNZ + 255) / 256, 256, 0, stream>>>(imRow, cntUser, NNZ);

    {
        int nb;
        nb = (NE + SCAN_B - 1) / SCAN_B;
        scan1<<<nb, SCAN_B, 0, stream>>>(cntEnt, arrEnt, part, NE);
        scan2<<<1, 1024, 0, stream>>>(part, nb);
        scan3<<<nb, SCAN_B, 0, stream>>>(arrEnt, part, NE);
        nb = (NN + SCAN_B - 1) / SCAN_B;
        scan1<<<nb, SCAN_B, 0, stream>>>(cntNode, arrNode, part, NN);
        scan2<<<1, 1024, 0, stream>>>(part, nb);
        scan3<<<nb, SCAN_B, 0, stream>>>(arrNode, part, NN);
        nb = (NU + SCAN_B - 1) / SCAN_B;
        scan1<<<nb, SCAN_B, 0, stream>>>(cntUser, arrUser, part, NU);
        scan2<<<1, 1024, 0, stream>>>(part, nb);
        scan3<<<nb, SCAN_B, 0, stream>>>(arrUser, part, NU);
    }

    fill_pair<<<(E + 255) / 256, 256, 0, stream>>>(head, tail, etype, -1, arrEnt, pairsEnt, E);
    fill_pair<<<(E2 + 255) / 256, 256, 0, stream>>>(eh, et, xtype, 0, arrNode, pairsNode, E2);
    fill_user<<<(NNZ + 255) / 256, 256, 0, stream>>>(imRow, imCol, imVal, arrUser, ucol, uval, NNZ);

    // ---- 3 hops of gathers ----
    const float* entCurP  = ent_emb;   float* entNewP  = entOut;
    const float* nodeOldP = user_emb;  float* nodeNewP = nodeU_A;

    for (int hop = 0; hop < 3; ++hop) {
        ent_gather<<<(NE + 3) / 4, 256, 0, stream>>>(
            entCurP, (const float4*)weight, arrEnt, pairsEnt, entNewP, entNorm, NE);
        node_gather<<<(NN + 3) / 4, 256, 0, stream>>>(
            nodeOldP, entCurP, (const float4*)extraW, arrNode, pairsNode,
            nodeNewP, outNodeRes, NN, NU);
        user_gather<<<(NU + 3) / 4, 256, 0, stream>>>(
            entNewP, entNorm, arrUser, ucol, uval, outUserRes, NU);

        if (hop == 0) {
            entCurP = entOut;  entNewP = entA;
            nodeOldP = nodeU_A; nodeNewP = nodeU_B;
        } else if (hop == 1) {
            entCurP = entA;    entNewP = entOut;
            nodeOldP = nodeU_B; nodeNewP = nodeU_A;
        }
    }
}